// Round 8
// baseline (558.246 us; speedup 1.0000x reference)
//
#include <hip/hip_runtime.h>
#include <math.h>

// ---- problem constants ----
#define NNODE 6144
#define SEG   512
#define NCH   14
#define XD    42          // NCH*3
#define ED    64          // embed dim
#define HD    128
#define NCLS  25
#define KN    9
#define NPB   14          // nodes per edge-block
#define ROWS  128         // NPB*KN = 126, padded to 128
#define EDGE_BLOCKS ((NNODE + NPB - 1) / NPB)   // 439

typedef __attribute__((ext_vector_type(8))) short short8;
typedef __attribute__((ext_vector_type(4))) short short4v;
typedef __attribute__((ext_vector_type(4))) float f32x4;

__device__ __forceinline__ float silu_f(float x) {
  return x / (1.0f + __expf(-x));
}
// bf16 round-nearest-even convert (finite inputs only)
__device__ __forceinline__ short f2bf(float x) {
  unsigned u = __builtin_bit_cast(unsigned, x);
  unsigned r = (u + 0x7fffu + ((u >> 16) & 1u)) >> 16;
  return (short)r;
}
__device__ __forceinline__ float bf2f(short s) {
  unsigned u = ((unsigned)(unsigned short)s) << 16;
  return __builtin_bit_cast(float, u);
}
__device__ __forceinline__ f32x4 mfma16(short8 a, short8 b, f32x4 c) {
  return __builtin_amdgcn_mfma_f32_16x16x32_bf16(a, b, c, 0, 0, 0);
}
// XOR swizzle: flip elem bits 3..5 by row&7 (16B granules)
__device__ __forceinline__ int swz128(int row, int col) {
  return row * 128 + (col ^ ((row & 7) << 3));
}
__device__ __forceinline__ int swz256(int row, int col) {
  return row * 256 + (col ^ ((row & 7) << 3));
}
__device__ __forceinline__ int swz64(int row, int col) {
  return row * 64 + (col ^ ((row & 7) << 3));
}

// Wbf layout (shorts): per layer l: l*114688 + {0:eW1T[128n][256k], 32768:eW2T,
// 49152:cW1T, 65536:nW1T[128n][256k], 98304:nW2T}; extras at EXOFF:
// mW1T[128n][128k], +16384 mW2T[64n][128k], +24576 W_inT[128n][64k]
#define EXOFF 344064
#define WBF_SHORTS (EXOFF + 32768)

// ---------------------------------------------------------------------------
// weight prep: bf16 [N][K] transposed copies of all GEMM weights
// ---------------------------------------------------------------------------
__global__ __launch_bounds__(256) void prep_weights(
    const float* __restrict__ eW1, const float* __restrict__ eW2,
    const float* __restrict__ cW1, const float* __restrict__ nW1,
    const float* __restrict__ nW2, const float* __restrict__ mW1,
    const float* __restrict__ mW2, const float* __restrict__ W_in,
    short* __restrict__ out)
{
  const int idx = blockIdx.x * 256 + threadIdx.x;
  if (blockIdx.y == 15) {
    if (idx < 16384) {                       // mW1T [128][128]
      const int n = idx >> 7, k = idx & 127;
      out[EXOFF + idx] = f2bf(mW1[k * HD + n]);
    } else if (idx < 24576) {                // mW2T [64][128]
      const int local = idx - 16384;
      const int n = local >> 7, k = local & 127;
      out[EXOFF + 16384 + local] = f2bf(mW2[k * ED + n]);
    } else if (idx < 32768) {                // W_inT [128][64]
      const int local = idx - 24576;
      const int n = local >> 6, k = local & 63;
      out[EXOFF + 24576 + local] = f2bf(W_in[k * HD + n]);
    }
    return;
  }
  const int mat = blockIdx.y % 5, l = blockIdx.y / 5;
  const int K = (mat == 0 || mat == 3) ? 256 : 128;
  if (idx >= K * 128) return;
  const int n = idx / K, k = idx - n * K;
  const float* src;
  switch (mat) {
    case 0: src = eW1 + (size_t)l * 257 * 128; break;   // rows 0..255 (radial row fp32)
    case 1: src = eW2 + (size_t)l * 128 * 128; break;
    case 2: src = cW1 + (size_t)l * 128 * 128; break;
    case 3: src = nW1 + (size_t)l * 256 * 128; break;
    default: src = nW2 + (size_t)l * 128 * 128; break;
  }
  const int dofs[5] = {0, 32768, 49152, 65536, 98304};
  out[(size_t)l * 114688 + dofs[mat] + idx] = f2bf(src[k * 128 + n]);
}

// ---------------------------------------------------------------------------
__global__ void copy_kernel(const float* __restrict__ src, float* __restrict__ dst, int n) {
  int i = blockIdx.x * blockDim.x + threadIdx.x;
  if (i < n) dst[i] = src[i];
}

// ---------------------------------------------------------------------------
// h_init_mfma: 16 nodes/block (384 blocks), 512 threads.
// Rounds>=1: A=silu(Hmem); u=silu(A@mW1+mb1); h0=embed[S]+(u@mW2+mb2);
// Round 0:   h0=embed[S].
// Then H=h0@W_in+b_in -> Hout (fp32) ; PQ0 = H@[W1a|W1b] (bf16) for layer 0.
// ---------------------------------------------------------------------------
__global__ __launch_bounds__(512) void h_init_mfma(
    const float* __restrict__ embed, const int* __restrict__ S,
    const short* __restrict__ W_inT, const float* __restrict__ b_in,
    const float* __restrict__ Hmem,
    const short* __restrict__ mW1T, const float* __restrict__ mb1,
    const short* __restrict__ mW2T, const float* __restrict__ mb2,
    const short* __restrict__ W1T0,
    float* __restrict__ Hout, short* __restrict__ PQ0)
{
  __shared__ __align__(16) short A[16 * HD];
  __shared__ __align__(16) short Bu[16 * HD];
  __shared__ __align__(16) short h0B[16 * ED];
  __shared__ __align__(16) short HB[16 * HD];
  const int t = threadIdx.x;
  const int m0 = blockIdx.x * 16;
  const int wid = t >> 6, lane = t & 63, lr = lane & 15, lk = lane >> 4;

  if (Hmem) {
    {
      const int r = t >> 5, c4 = t & 31;
      const float4 v = ((const float4*)Hmem)[(size_t)(m0 + r) * 32 + c4];
      short4v s;
      s.x = f2bf(silu_f(v.x)); s.y = f2bf(silu_f(v.y));
      s.z = f2bf(silu_f(v.z)); s.w = f2bf(silu_f(v.w));
      *(short4v*)&A[swz128(r, c4 * 4)] = s;
    }
    __syncthreads();
    {  // u = silu(A @ mW1T + mb1) -> Bu
      f32x4 acc[2] = {};
#pragma unroll
      for (int ks = 0; ks < 4; ++ks) {
        const int k0 = ks * 32 + lk * 8;
        const short8 a = *(const short8*)&A[swz128(lr, k0)];
#pragma unroll
        for (int ni = 0; ni < 2; ++ni) {
          const int c = (wid * 2 + ni) * 16 + lr;
          acc[ni] = mfma16(a, *(const short8*)(mW1T + c * 128 + k0), acc[ni]);
        }
      }
#pragma unroll
      for (int ni = 0; ni < 2; ++ni) {
        const int col = (wid * 2 + ni) * 16 + lr;
        const float bias = mb1[col];
#pragma unroll
        for (int g = 0; g < 4; ++g)
          Bu[swz128(lk * 4 + g, col)] = f2bf(silu_f(acc[ni][g] + bias));
      }
    }
    __syncthreads();
    if (wid < 4) {  // h0 = embed[S] + u @ mW2T + mb2 (64 cols)
      f32x4 acc = {};
#pragma unroll
      for (int ks = 0; ks < 4; ++ks) {
        const int k0 = ks * 32 + lk * 8;
        const short8 a = *(const short8*)&Bu[swz128(lr, k0)];
        const int c = wid * 16 + lr;
        acc = mfma16(a, *(const short8*)(mW2T + c * 128 + k0), acc);
      }
      const int col = wid * 16 + lr;
      const float bias = mb2[col];
#pragma unroll
      for (int g = 0; g < 4; ++g) {
        const int row = lk * 4 + g;
        h0B[swz64(row, col)] = f2bf(embed[S[m0 + row] * ED + col] + acc[g] + bias);
      }
    }
  } else {
    for (int idx = t; idx < 16 * ED; idx += 512) {
      const int row = idx >> 6, col = idx & 63;
      h0B[swz64(row, col)] = f2bf(embed[S[m0 + row] * ED + col]);
    }
  }
  __syncthreads();
  {  // H = h0 @ W_inT + b_in -> Hout global fp32 + HB bf16
    f32x4 acc = {};
#pragma unroll
    for (int ks = 0; ks < 2; ++ks) {
      const int k0 = ks * 32 + lk * 8;
      const short8 a = *(const short8*)&h0B[swz64(lr, k0)];
      const int c = wid * 16 + lr;
      acc = mfma16(a, *(const short8*)(W_inT + c * 64 + k0), acc);
    }
    const int col = wid * 16 + lr;
    const float bias = b_in[col];
#pragma unroll
    for (int g = 0; g < 4; ++g) {
      const int row = lk * 4 + g;
      const float hv = acc[g] + bias;
      Hout[(size_t)(m0 + row) * HD + col] = hv;
      HB[swz128(row, col)] = f2bf(hv);
    }
  }
  __syncthreads();
  {  // PQ0 = HB @ [W1a|W1b]  (256 cols, 2 n-tiles/wave)
    f32x4 acc[2] = {};
#pragma unroll
    for (int ks = 0; ks < 4; ++ks) {
      const int k0 = ks * 32 + lk * 8;
      const short8 a = *(const short8*)&HB[swz128(lr, k0)];
#pragma unroll
      for (int ni = 0; ni < 2; ++ni) {
        const int c = (wid * 2 + ni) * 16 + lr;
        const short* bp = (c < HD) ? (W1T0 + c * 256 + k0)
                                   : (W1T0 + (c - HD) * 256 + HD + k0);
        acc[ni] = mfma16(a, *(const short8*)bp, acc[ni]);
      }
    }
#pragma unroll
    for (int ni = 0; ni < 2; ++ni) {
      const int c = (wid * 2 + ni) * 16 + lr;
#pragma unroll
      for (int g = 0; g < 4; ++g)
        PQ0[(size_t)(m0 + lk * 4 + g) * 256 + c] = f2bf(acc[ni][g]);
    }
  }
}

// ---------------------------------------------------------------------------
// kNN: one wave per node, 8 nodes/block, candidates in registers, no barriers.
// ---------------------------------------------------------------------------
__global__ __launch_bounds__(512) void knn_kernel(const float* __restrict__ X,
                                                  int* __restrict__ nbr)
{
  const int w = threadIdx.x >> 6, lane = threadIdx.x & 63;
  const int i = blockIdx.x * 8 + w;
  const int base = (i / SEG) * SEG;

  const float cx = X[i * XD + 3], cy = X[i * XD + 4], cz = X[i * XD + 5];
  float dv[8];
  int   di[8];
#pragma unroll
  for (int q = 0; q < 8; ++q) {
    const int j = base + lane + q * 64;
    float dx = __fsub_rn(cx, X[j * XD + 3]);
    float dy = __fsub_rn(cy, X[j * XD + 4]);
    float dz = __fsub_rn(cz, X[j * XD + 5]);
    float d2 = __fadd_rn(__fadd_rn(__fmul_rn(dx, dx), __fmul_rn(dy, dy)), __fmul_rn(dz, dz));
    if (j == i) d2 = 1e9f;
    dv[q] = d2; di[q] = j;
  }
  for (int it = 0; it < KN; ++it) {
    float bv = dv[0]; int bi = di[0];
#pragma unroll
    for (int q = 1; q < 8; ++q)
      if (dv[q] < bv || (dv[q] == bv && di[q] < bi)) { bv = dv[q]; bi = di[q]; }
#pragma unroll
    for (int m = 1; m < 64; m <<= 1) {
      float ov = __shfl_xor(bv, m, 64);
      int   oi = __shfl_xor(bi, m, 64);
      if (ov < bv || (ov == bv && oi < bi)) { bv = ov; bi = oi; }
    }
    if (lane == 0) nbr[i * KN + it] = bi;
    const int rel = bi - base;
    const int oq = rel >> 6;
#pragma unroll
    for (int q = 0; q < 8; ++q)
      if (q == oq && (rel & 63) == lane) dv[q] = 3e38f;
  }
}

// ---------------------------------------------------------------------------
// Fused per-layer edge kernel, fat-block version:
// 14 nodes (126 edges -> 128 rows) per block, 1024 threads = 16 waves.
// 439 blocks, LDS 78.8 KB -> 2 blocks/CU, 32 waves/CU (100% cap), no tail.
// Phases: P01 | G2 | G3+scale+agg | NG1(w0-7)+X(w8-15) | NG2(w0-7) | [PQn all].
// ---------------------------------------------------------------------------
__global__ __launch_bounds__(1024) void edge_layer_kernel(
    const float* __restrict__ Hin,  float* __restrict__ Hout,
    const float* __restrict__ Xin,  float* __restrict__ Xout,
    const int*   __restrict__ nbr,  const float* __restrict__ channel_w,
    const short* __restrict__ PQ,
    const float* __restrict__ eW1,  const float* __restrict__ eb1,
    const float* __restrict__ eb2,  const float* __restrict__ cb1,
    const float* __restrict__ cW2,  const float* __restrict__ cb2,
    const float* __restrict__ nb1,  const float* __restrict__ nb2,
    const short* __restrict__ W2T,  const short* __restrict__ C1T,
    const short* __restrict__ N1T,  const short* __restrict__ N2T,
    const short* __restrict__ W1Tn, short* __restrict__ PQn)
{
  __shared__ __align__(16) short bufA[ROWS * HD];    // h1; later Hout bf16 (32 KB)
  __shared__ __align__(16) short bufB[ROWS * HD];    // msg               (32 KB)
  __shared__ __align__(16) short nodeA[NPB * 256];   // [Hi | agg]        (7 KB)
  __shared__ __align__(16) short uT[NPB * HD];       // node hidden       (3.5 KB)
  __shared__ float scalePart[ROWS][4];               // (2 KB)
  __shared__ int   nbrS[ROWS];
  short* houtB = bufA;   // bufA dead after G2; reused for Hout bf16

  const int t  = threadIdx.x;
  const int n0 = blockIdx.x * NPB;
  const int nvalid = (NNODE - n0 < NPB) ? (NNODE - n0) : NPB;
  const int evalid = nvalid * KN;

  // ---- P01: nbr + radial (8 thr/row, shfl-reduced) + h1 + nodeA-Hi ----
  {
    const int row  = t >> 3;          // 0..127
    const int part = t & 7;           // 0..7
    const bool rvalid = row < evalid;
    const int nd = row / KN;
    const int jn = rvalid ? nbr[n0 * KN + row] : n0;
    if (part == 0) nbrS[row] = jn;

    float r = 0.f;
    {
      const float* xi = Xin + (size_t)(n0 + ((nd < nvalid) ? nd : 0)) * XD;
      const float* xj = Xin + (size_t)jn * XD;
#pragma unroll
      for (int ii = 0; ii < 6; ++ii) {
        const int e = part + ii * 8;
        if (e < XD) {
          float d = 0.f;
          if (rvalid) d = xi[e] - xj[e];
          r = fmaf(channel_w[e / 3] * d, d, r);
        }
      }
    }
    r += __shfl_xor(r, 1, 64);
    r += __shfl_xor(r, 2, 64);
    r += __shfl_xor(r, 4, 64);

    // nodeA Hi half (448 threads)
    if (t < NPB * (HD / 4)) {
      const int r2 = t >> 5, c4 = t & 31;
      float4 v = make_float4(0.f, 0.f, 0.f, 0.f);
      if (r2 < nvalid) v = ((const float4*)Hin)[(size_t)(n0 + r2) * 32 + c4];
      short4v s;
      s.x = f2bf(v.x); s.y = f2bf(v.y); s.z = f2bf(v.z); s.w = f2bf(v.w);
      *(short4v*)&nodeA[swz256(r2, c4 * 4)] = s;
    }

    // h1 = silu(P[i] + Q[j] + radial*w256 + eb1) -> bufA (this thread: 4 c4)
    const int inode = n0 + ((nd < nvalid) ? nd : 0);
    const short4v* PQv = (const short4v*)PQ;
    const float4* w2564 = (const float4*)(eW1 + 256 * HD);
    const float4* eb14 = (const float4*)eb1;
#pragma unroll
    for (int ii = 0; ii < 4; ++ii) {
      const int c4 = part + ii * 8;
      const short4v ps = PQv[(size_t)inode * 64 + c4];
      const short4v qs = PQv[(size_t)jn * 64 + 32 + c4];
      const float4 w = w2564[c4];
      const float4 bb = eb14[c4];
      short4v s;
      s.x = f2bf(silu_f(bf2f(ps.x) + bf2f(qs.x) + r * w.x + bb.x));
      s.y = f2bf(silu_f(bf2f(ps.y) + bf2f(qs.y) + r * w.y + bb.y));
      s.z = f2bf(silu_f(bf2f(ps.z) + bf2f(qs.z) + r * w.z + bb.z));
      s.w = f2bf(silu_f(bf2f(ps.w) + bf2f(qs.w) + r * w.w + bb.w));
      *(short4v*)&bufA[swz128(row, c4 * 4)] = s;
    }
  }
  __syncthreads();

  const int wid  = t >> 6;       // 0..15
  const int lane = t & 63;
  const int m2 = wid >> 2;       // 0..3
  const int n2 = wid & 3;        // 0..3
  const int lr = lane & 15;
  const int lk = lane >> 4;
  const int rA0 = m2 * 32 + lr;
  const int rA1 = rA0 + 16;

  // ---- G2: msg = silu(h1 @ eW2 + eb2) -> bufB ----
  {
    f32x4 acc[2][2] = {};
    const short* b0p = W2T + ((n2 * 2) * 16 + lr) * 128;
    const short* b1p = b0p + 16 * 128;
#pragma unroll
    for (int ks = 0; ks < 4; ++ks) {
      const int k0 = ks * 32 + lk * 8;
      const short8 a0 = *(const short8*)&bufA[swz128(rA0, k0)];
      const short8 a1 = *(const short8*)&bufA[swz128(rA1, k0)];
      const short8 b0 = *(const short8*)(b0p + k0);
      const short8 b1 = *(const short8*)(b1p + k0);
      acc[0][0] = mfma16(a0, b0, acc[0][0]);
      acc[0][1] = mfma16(a0, b1, acc[0][1]);
      acc[1][0] = mfma16(a1, b0, acc[1][0]);
      acc[1][1] = mfma16(a1, b1, acc[1][1]);
    }
#pragma unroll
    for (int ni = 0; ni < 2; ++ni) {
      const int col = (n2 * 2 + ni) * 16 + lr;
      const float bias = eb2[col];
#pragma unroll
      for (int mi = 0; mi < 2; ++mi) {
        const int rb = (m2 * 2 + mi) * 16 + lk * 4;
#pragma unroll
        for (int g = 0; g < 4; ++g)
          bufB[swz128(rb + g, col)] = f2bf(silu_f(acc[mi][ni][g] + bias));
      }
    }
  }
  __syncthreads();

  // ---- G3: scale partials in-register; agg (u32-paired) -> nodeA ----
  {
    f32x4 acc[2][2] = {};
    const short* b0p = C1T + ((n2 * 2) * 16 + lr) * 128;
    const short* b1p = b0p + 16 * 128;
#pragma unroll
    for (int ks = 0; ks < 4; ++ks) {
      const int k0 = ks * 32 + lk * 8;
      const short8 a0 = *(const short8*)&bufB[swz128(rA0, k0)];
      const short8 a1 = *(const short8*)&bufB[swz128(rA1, k0)];
      const short8 b0 = *(const short8*)(b0p + k0);
      const short8 b1 = *(const short8*)(b1p + k0);
      acc[0][0] = mfma16(a0, b0, acc[0][0]);
      acc[0][1] = mfma16(a0, b1, acc[0][1]);
      acc[1][0] = mfma16(a1, b0, acc[1][0]);
      acc[1][1] = mfma16(a1, b1, acc[1][1]);
    }
    float p[2][4];
#pragma unroll
    for (int mi = 0; mi < 2; ++mi)
#pragma unroll
      for (int g = 0; g < 4; ++g) p[mi][g] = 0.f;
#pragma unroll
    for (int ni = 0; ni < 2; ++ni) {
      const int col = (n2 * 2 + ni) * 16 + lr;
      const float bias = cb1[col];
      const float wv = cW2[col];
#pragma unroll
      for (int mi = 0; mi < 2; ++mi)
#pragma unroll
        for (int g = 0; g < 4; ++g)
          p[mi][g] = fmaf(silu_f(acc[mi][ni][g] + bias), wv, p[mi][g]);
    }
#pragma unroll
    for (int m = 1; m < 16; m <<= 1) {
#pragma unroll
      for (int mi = 0; mi < 2; ++mi)
#pragma unroll
        for (int g = 0; g < 4; ++g)
          p[mi][g] += __shfl_xor(p[mi][g], m, 64);
    }
    if (lr == 0) {
#pragma unroll
      for (int mi = 0; mi < 2; ++mi)
#pragma unroll
        for (int g = 0; g < 4; ++g)
          scalePart[(m2 * 2 + mi) * 16 + lk * 4 + g][n2] = p[mi][g];
    }
  }
  if (t < NPB * (HD / 2)) {   // agg: 896 threads, col pairs via u32 reads
    const int r2 = t >> 6, cp = (t & 63) * 2;
    float v0 = 0.f, v1 = 0.f;
    if (r2 < nvalid) {
#pragma unroll
      for (int k = 0; k < KN; ++k) {
        const unsigned w = *(const unsigned*)&bufB[swz128(r2 * KN + k, cp)];
        v0 += bf2f((short)(w & 0xffffu));
        v1 += bf2f((short)(w >> 16));
      }
    }
    const unsigned lo = (unsigned short)f2bf(v0);
    const unsigned hi = (unsigned short)f2bf(v1);
    *(unsigned*)&nodeA[swz256(r2, cp + HD)] = lo | (hi << 16);
  }
  __syncthreads();

  // ---- P5: NG1 on waves 0-7 ; X update (global gather) on waves 8-15 ----
  if (wid < 8) {
    f32x4 acc = {};
    const short* bp = N1T + (wid * 16 + lr) * 256;
#pragma unroll
    for (int ks = 0; ks < 8; ++ks) {
      const int k0 = ks * 32 + lk * 8;
      short8 a = {0, 0, 0, 0, 0, 0, 0, 0};
      if (lr < NPB) a = *(const short8*)&nodeA[swz256(lr, k0)];
      const short8 b = *(const short8*)(bp + k0);
      acc = mfma16(a, b, acc);
    }
    const int col = wid * 16 + lr;
    const float bias = nb1[col];
#pragma unroll
    for (int g = 0; g < 4; ++g) {
      const int orow = lk * 4 + g;
      if (orow < NPB) uT[swz128(orow, col)] = f2bf(silu_f(acc[g] + bias));
    }
  } else {
    const float c2 = cb2[0];
    const int t2 = t - 512;
    for (int idx = t2; idx < NPB * XD; idx += 512) {
      const int nd = idx / XD, e = idx - nd * XD;
      if (nd < nvalid) {
        const float xi = Xin[(size_t)n0 * XD + idx];
        float a = 0.f;
#pragma unroll
        for (int k = 0; k < KN; ++k) {
          const int r = nd * KN + k;
          const float sc = ((scalePart[r][0] + scalePart[r][1])
                          + (scalePart[r][2] + scalePart[r][3])) + c2;
          a = fmaf(xi - Xin[(size_t)nbrS[r] * XD + e], sc, a);
        }
        Xout[(size_t)n0 * XD + idx] = xi + a / 9.0f;
      }
    }
  }
  __syncthreads();

  // ---- NG2 (waves 0-7): Hout = Hi + u @ nW2 + nb2 (+ stash bf16 houtB) ----
  if (wid < 8) {
    f32x4 acc = {};
    const short* bp = N2T + (wid * 16 + lr) * 128;
#pragma unroll
    for (int ks = 0; ks < 4; ++ks) {
      const int k0 = ks * 32 + lk * 8;
      short8 a = {0, 0, 0, 0, 0, 0, 0, 0};
      if (lr < NPB) a = *(const short8*)&uT[swz128(lr, k0)];
      const short8 b = *(const short8*)(bp + k0);
      acc = mfma16(a, b, acc);
    }
    const int col = wid * 16 + lr;
    const float bias = nb2[col];
#pragma unroll
    for (int g = 0; g < 4; ++g) {
      const int row = lk * 4 + g;
      if (row < nvalid) {
        const float hv = Hin[(size_t)(n0 + row) * HD + col] + acc[g] + bias;
        Hout[(size_t)(n0 + row) * HD + col] = hv;
        if (W1Tn) houtB[swz128(row, col)] = f2bf(hv);
      }
    }
  }

  // ---- PQn (all 16 waves): next layer's PQ = Hout @ [W1a|W1b] ----
  if (W1Tn) {
    __syncthreads();
    f32x4 acc = {};
    const int c = wid * 16 + lr;     // 0..255
    const short* bp = (c < HD) ? (W1Tn + c * 256)
                               : (W1Tn + (c - HD) * 256 + HD);
#pragma unroll
    for (int ks = 0; ks < 4; ++ks) {
      const int k0 = ks * 32 + lk * 8;
      short8 a = {0, 0, 0, 0, 0, 0, 0, 0};
      if (lr < NPB) a = *(const short8*)&houtB[swz128(lr, k0)];
      acc = mfma16(a, *(const short8*)(bp + k0), acc);
    }
#pragma unroll
    for (int g = 0; g < 4; ++g) {
      const int row = lk * 4 + g;
      if (row < nvalid) PQn[(size_t)(n0 + row) * 256 + c] = f2bf(acc[g]);
    }
  }
}

// ---------------------------------------------------------------------------
// Output head (4-way ILP unroll)
// ---------------------------------------------------------------------------
__global__ __launch_bounds__(128) void out_kernel(
    const float* __restrict__ H, const float* __restrict__ X,
    const float* __restrict__ oW1, const float* __restrict__ ob1,
    const float* __restrict__ oW2, const float* __restrict__ ob2,
    float* __restrict__ out)
{
  __shared__ float hs[HD];
  __shared__ float u[HD];
  const int i = blockIdx.x, j = threadIdx.x;

  hs[j] = silu_f(H[i * HD + j]);
  __syncthreads();
  float a0 = 0.f, a1 = 0.f, a2 = 0.f, a3 = 0.f;
  for (int k = 0; k < HD; k += 4) {
    a0 = fmaf(hs[k + 0], oW1[(k + 0) * HD + j], a0);
    a1 = fmaf(hs[k + 1], oW1[(k + 1) * HD + j], a1);
    a2 = fmaf(hs[k + 2], oW1[(k + 2) * HD + j], a2);
    a3 = fmaf(hs[k + 3], oW1[(k + 3) * HD + j], a3);
  }
  u[j] = silu_f(ob1[j] + ((a0 + a1) + (a2 + a3)));
  __syncthreads();
  if (j < NCLS) {
    float o0 = 0.f, o1 = 0.f, o2 = 0.f, o3 = 0.f;
    for (int k = 0; k < HD; k += 4) {
      o0 = fmaf(u[k + 0], oW2[(k + 0) * NCLS + j], o0);
      o1 = fmaf(u[k + 1], oW2[(k + 1) * NCLS + j], o1);
      o2 = fmaf(u[k + 2], oW2[(k + 2) * NCLS + j], o2);
      o3 = fmaf(u[k + 3], oW2[(k + 3) * NCLS + j], o3);
    }
    out[i * NCLS + j] = ob2[j] + ((o0 + o1) + (o2 + o3));
  }
  if (j < XD) out[NNODE * NCLS + i * XD + j] = X[i * XD + j];
}

// ---------------------------------------------------------------------------
extern "C" void kernel_launch(void* const* d_in, const int* in_sizes, int n_in,
                              void* d_out, int out_size, void* d_ws, size_t ws_size,
                              hipStream_t stream)
{
  const float* X0       = (const float*)d_in[0];
  const int*   S        = (const int*)  d_in[1];
  const float* embed    = (const float*)d_in[3];
  const float* W_in     = (const float*)d_in[4];
  const float* b_in     = (const float*)d_in[5];
  const float* channelw = (const float*)d_in[6];
  const float* eW1      = (const float*)d_in[7];
  const float* eb1      = (const float*)d_in[8];
  const float* eW2      = (const float*)d_in[9];
  const float* eb2      = (const float*)d_in[10];
  const float* cW1      = (const float*)d_in[11];
  const float* cb1      = (const float*)d_in[12];
  const float* cW2      = (const float*)d_in[13];
  const float* cb2      = (const float*)d_in[14];
  const float* nW1      = (const float*)d_in[15];
  const float* nb1      = (const float*)d_in[16];
  const float* nW2      = (const float*)d_in[17];
  const float* nb2      = (const float*)d_in[18];
  const float* mW1      = (const float*)d_in[19];
  const float* mb1      = (const float*)d_in[20];
  const float* mW2      = (const float*)d_in[21];
  const float* mb2      = (const float*)d_in[22];
  const float* oW1      = (const float*)d_in[23];
  const float* ob1      = (const float*)d_in[24];
  const float* oW2      = (const float*)d_in[25];
  const float* ob2      = (const float*)d_in[26];

  char* ws = (char*)d_ws;
  const size_t HBYTES = (size_t)NNODE * HD * sizeof(float);      // 3,145,728
  const size_t XBYTES = (size_t)NNODE * XD * sizeof(float);      // 1,032,192
  const size_t NBRB   = (size_t)NNODE * KN * sizeof(int);        // 221,184
  const size_t WBFB   = (size_t)WBF_SHORTS * sizeof(short);      // 753,664
  const size_t PQB    = (size_t)NNODE * 256 * sizeof(short);     // 3,145,728
  float* Hb[2] = { (float*)(ws), (float*)(ws + HBYTES) };
  float* Xb[2] = { (float*)(ws + 2 * HBYTES), (float*)(ws + 2 * HBYTES + XBYTES) };
  int*   nbr   = (int*)(ws + 2 * HBYTES + 2 * XBYTES);
  short* Wbf   = (short*)(ws + 2 * HBYTES + 2 * XBYTES + NBRB);
  short* PQb[2] = { (short*)(ws + 2 * HBYTES + 2 * XBYTES + NBRB + WBFB),
                    (short*)(ws + 2 * HBYTES + 2 * XBYTES + NBRB + WBFB + PQB) };

  prep_weights<<<dim3(128, 16), 256, 0, stream>>>(eW1, eW2, cW1, nW1, nW2,
                                                  mW1, mW2, W_in, Wbf);
  copy_kernel<<<(NNODE * XD + 255) / 256, 256, 0, stream>>>(X0, Xb[0], NNODE * XD);

  int hc = 0, xc = 0;
  for (int t = 0; t < 3; ++t) {
    const float* Hmem = (t == 0) ? nullptr : Hb[hc];
    h_init_mfma<<<NNODE / 16, 512, 0, stream>>>(
        embed, S, Wbf + EXOFF + 24576, b_in, Hmem,
        Wbf + EXOFF, mb1, Wbf + EXOFF + 16384, mb2,
        Wbf /* layer-0 eW1T */, Hb[hc ^ 1], PQb[0]);
    hc ^= 1;
    knn_kernel<<<NNODE / 8, 512, 0, stream>>>(Xb[xc], nbr);
    for (int l = 0; l < 3; ++l) {
      const short* Wl = Wbf + (size_t)l * 114688;
      const short* Wn = (l < 2) ? (Wbf + (size_t)(l + 1) * 114688) : nullptr;
      const short* pqr = (l == 1) ? PQb[1] : PQb[0];
      short* pqw = (l == 0) ? PQb[1] : ((l == 1) ? PQb[0] : nullptr);
      edge_layer_kernel<<<EDGE_BLOCKS, 1024, 0, stream>>>(
          Hb[hc], Hb[hc ^ 1], Xb[xc], Xb[xc ^ 1], nbr, channelw, pqr,
          eW1 + (size_t)l * 257 * HD, eb1 + (size_t)l * HD,
          eb2 + (size_t)l * HD,  cb1 + (size_t)l * HD,
          cW2 + (size_t)l * HD,  cb2 + (size_t)l,
          nb1 + (size_t)l * HD,  nb2 + (size_t)l * HD,
          Wl + 32768, Wl + 49152, Wl + 65536, Wl + 98304,
          Wn, pqw);
      hc ^= 1; xc ^= 1;
    }
  }
  out_kernel<<<NNODE, HD, 0, stream>>>(Hb[hc], Xb[xc], oW1, ob1, oW2, ob2, (float*)d_out);
}

// Round 10
// 535.542 us; speedup vs baseline: 1.0424x; 1.0424x over previous
//
#include <hip/hip_runtime.h>
#include <hip/hip_bf16.h>
#include <math.h>

// ---- problem constants ----
#define NNODE 6144
#define SEG   512
#define NCH   14
#define XD    42          // NCH*3
#define ED    64          // embed dim
#define HD    128
#define NCLS  25
#define KN    9
#define NPB   7           // nodes per edge-block
#define ROWS  64          // NPB*KN = 63, padded to 64
#define EDGE_BLOCKS ((NNODE + NPB - 1) / NPB)

typedef __attribute__((ext_vector_type(8))) short short8;
typedef __attribute__((ext_vector_type(4))) short short4v;
typedef __attribute__((ext_vector_type(4))) float f32x4;

__device__ __forceinline__ float silu_f(float x) {
  return x / (1.0f + __expf(-x));
}
// bf16 converts via HW cvt (RNE); __hip_bfloat16 is trivially copyable
__device__ __forceinline__ short f2bf(float x) {
  __hip_bfloat16 h = __float2bfloat16(x);
  return __builtin_bit_cast(short, h);
}
__device__ __forceinline__ unsigned pkbf(float lo, float hi) {
  return (unsigned)(unsigned short)f2bf(lo)
       | ((unsigned)(unsigned short)f2bf(hi) << 16);
}
__device__ __forceinline__ float bf2f(short s) {
  unsigned u = ((unsigned)(unsigned short)s) << 16;
  return __builtin_bit_cast(float, u);
}
__device__ __forceinline__ f32x4 mfma16(short8 a, short8 b, f32x4 c) {
  return __builtin_amdgcn_mfma_f32_16x16x32_bf16(a, b, c, 0, 0, 0);
}
// XOR swizzle: flip elem bits 3..5 by row&7 (16B granules)
__device__ __forceinline__ int swz128(int row, int col) {
  return row * 128 + (col ^ ((row & 7) << 3));
}
__device__ __forceinline__ int swz256(int row, int col) {
  return row * 256 + (col ^ ((row & 7) << 3));
}
__device__ __forceinline__ int swz64(int row, int col) {
  return row * 64 + (col ^ ((row & 7) << 3));
}

// Wbf layout (shorts): per layer l: l*114688 + {0:eW1T[128n][256k], 32768:eW2T,
// 49152:cW1T, 65536:nW1T[128n][256k], 98304:nW2T}; extras at EXOFF:
// mW1T[128n][128k], +16384 mW2T[64n][128k], +24576 W_inT[128n][64k]
#define EXOFF 344064
#define WBF_SHORTS (EXOFF + 32768)

// ---------------------------------------------------------------------------
// weight prep: bf16 [N][K] transposed copies of all GEMM weights
// ---------------------------------------------------------------------------
__global__ __launch_bounds__(256) void prep_weights(
    const float* __restrict__ eW1, const float* __restrict__ eW2,
    const float* __restrict__ cW1, const float* __restrict__ nW1,
    const float* __restrict__ nW2, const float* __restrict__ mW1,
    const float* __restrict__ mW2, const float* __restrict__ W_in,
    short* __restrict__ out)
{
  const int idx = blockIdx.x * 256 + threadIdx.x;
  if (blockIdx.y == 15) {
    if (idx < 16384) {                       // mW1T [128][128]
      const int n = idx >> 7, k = idx & 127;
      out[EXOFF + idx] = f2bf(mW1[k * HD + n]);
    } else if (idx < 24576) {                // mW2T [64][128]
      const int local = idx - 16384;
      const int n = local >> 7, k = local & 127;
      out[EXOFF + 16384 + local] = f2bf(mW2[k * ED + n]);
    } else if (idx < 32768) {                // W_inT [128][64]
      const int local = idx - 24576;
      const int n = local >> 6, k = local & 63;
      out[EXOFF + 24576 + local] = f2bf(W_in[k * HD + n]);
    }
    return;
  }
  const int mat = blockIdx.y % 5, l = blockIdx.y / 5;
  const int K = (mat == 0 || mat == 3) ? 256 : 128;
  if (idx >= K * 128) return;
  const int n = idx / K, k = idx - n * K;
  const float* src;
  switch (mat) {
    case 0: src = eW1 + (size_t)l * 257 * 128; break;   // rows 0..255 (radial row fp32)
    case 1: src = eW2 + (size_t)l * 128 * 128; break;
    case 2: src = cW1 + (size_t)l * 128 * 128; break;
    case 3: src = nW1 + (size_t)l * 256 * 128; break;
    default: src = nW2 + (size_t)l * 128 * 128; break;
  }
  const int dofs[5] = {0, 32768, 49152, 65536, 98304};
  out[(size_t)l * 114688 + dofs[mat] + idx] = f2bf(src[k * 128 + n]);
}

// ---------------------------------------------------------------------------
__global__ void copy_kernel(const float* __restrict__ src, float* __restrict__ dst, int n) {
  int i = blockIdx.x * blockDim.x + threadIdx.x;
  if (i < n) dst[i] = src[i];
}

// ---------------------------------------------------------------------------
// h_init_mfma: 16 nodes/block (384 blocks), 512 threads.
// ---------------------------------------------------------------------------
__global__ __launch_bounds__(512) void h_init_mfma(
    const float* __restrict__ embed, const int* __restrict__ S,
    const short* __restrict__ W_inT, const float* __restrict__ b_in,
    const float* __restrict__ Hmem,
    const short* __restrict__ mW1T, const float* __restrict__ mb1,
    const short* __restrict__ mW2T, const float* __restrict__ mb2,
    const short* __restrict__ W1T0,
    float* __restrict__ Hout, short* __restrict__ PQ0)
{
  __shared__ __align__(16) short A[16 * HD];
  __shared__ __align__(16) short Bu[16 * HD];
  __shared__ __align__(16) short h0B[16 * ED];
  __shared__ __align__(16) short HB[16 * HD];
  const int t = threadIdx.x;
  const int m0 = blockIdx.x * 16;
  const int wid = t >> 6, lane = t & 63, lr = lane & 15, lk = lane >> 4;

  if (Hmem) {
    {
      const int r = t >> 5, c4 = t & 31;
      const float4 v = ((const float4*)Hmem)[(size_t)(m0 + r) * 32 + c4];
      uint2 u;
      u.x = pkbf(silu_f(v.x), silu_f(v.y));
      u.y = pkbf(silu_f(v.z), silu_f(v.w));
      *(uint2*)&A[swz128(r, c4 * 4)] = u;
    }
    __syncthreads();
    {  // u = silu(A @ mW1T + mb1) -> Bu
      f32x4 acc[2] = {};
#pragma unroll
      for (int ks = 0; ks < 4; ++ks) {
        const int k0 = ks * 32 + lk * 8;
        const short8 a = *(const short8*)&A[swz128(lr, k0)];
#pragma unroll
        for (int ni = 0; ni < 2; ++ni) {
          const int c = (wid * 2 + ni) * 16 + lr;
          acc[ni] = mfma16(a, *(const short8*)(mW1T + c * 128 + k0), acc[ni]);
        }
      }
#pragma unroll
      for (int ni = 0; ni < 2; ++ni) {
        const int col = (wid * 2 + ni) * 16 + lr;
        const float bias = mb1[col];
#pragma unroll
        for (int g = 0; g < 4; ++g)
          Bu[swz128(lk * 4 + g, col)] = f2bf(silu_f(acc[ni][g] + bias));
      }
    }
    __syncthreads();
    if (wid < 4) {  // h0 = embed[S] + u @ mW2T + mb2 (64 cols)
      f32x4 acc = {};
#pragma unroll
      for (int ks = 0; ks < 4; ++ks) {
        const int k0 = ks * 32 + lk * 8;
        const short8 a = *(const short8*)&Bu[swz128(lr, k0)];
        const int c = wid * 16 + lr;
        acc = mfma16(a, *(const short8*)(mW2T + c * 128 + k0), acc);
      }
      const int col = wid * 16 + lr;
      const float bias = mb2[col];
#pragma unroll
      for (int g = 0; g < 4; ++g) {
        const int row = lk * 4 + g;
        h0B[swz64(row, col)] = f2bf(embed[S[m0 + row] * ED + col] + acc[g] + bias);
      }
    }
  } else {
    for (int idx = t; idx < 16 * ED; idx += 512) {
      const int row = idx >> 6, col = idx & 63;
      h0B[swz64(row, col)] = f2bf(embed[S[m0 + row] * ED + col]);
    }
  }
  __syncthreads();
  {  // H = h0 @ W_inT + b_in -> Hout global fp32 + HB bf16
    f32x4 acc = {};
#pragma unroll
    for (int ks = 0; ks < 2; ++ks) {
      const int k0 = ks * 32 + lk * 8;
      const short8 a = *(const short8*)&h0B[swz64(lr, k0)];
      const int c = wid * 16 + lr;
      acc = mfma16(a, *(const short8*)(W_inT + c * 64 + k0), acc);
    }
    const int col = wid * 16 + lr;
    const float bias = b_in[col];
#pragma unroll
    for (int g = 0; g < 4; ++g) {
      const int row = lk * 4 + g;
      const float hv = acc[g] + bias;
      Hout[(size_t)(m0 + row) * HD + col] = hv;
      HB[swz128(row, col)] = f2bf(hv);
    }
  }
  __syncthreads();
  {  // PQ0 = HB @ [W1a|W1b]  (256 cols, 2 n-tiles/wave)
    f32x4 acc[2] = {};
#pragma unroll
    for (int ks = 0; ks < 4; ++ks) {
      const int k0 = ks * 32 + lk * 8;
      const short8 a = *(const short8*)&HB[swz128(lr, k0)];
#pragma unroll
      for (int ni = 0; ni < 2; ++ni) {
        const int c = (wid * 2 + ni) * 16 + lr;
        const short* bp = (c < HD) ? (W1T0 + c * 256 + k0)
                                   : (W1T0 + (c - HD) * 256 + HD + k0);
        acc[ni] = mfma16(a, *(const short8*)bp, acc[ni]);
      }
    }
#pragma unroll
    for (int ni = 0; ni < 2; ++ni) {
      const int c = (wid * 2 + ni) * 16 + lr;
#pragma unroll
      for (int g = 0; g < 4; ++g)
        PQ0[(size_t)(m0 + lk * 4 + g) * 256 + c] = f2bf(acc[ni][g]);
    }
  }
}

// ---------------------------------------------------------------------------
// kNN: one wave per node, 8 nodes/block, candidates in registers, no barriers.
// ---------------------------------------------------------------------------
__global__ __launch_bounds__(512) void knn_kernel(const float* __restrict__ X,
                                                  int* __restrict__ nbr)
{
  const int w = threadIdx.x >> 6, lane = threadIdx.x & 63;
  const int i = blockIdx.x * 8 + w;
  const int base = (i / SEG) * SEG;

  const float cx = X[i * XD + 3], cy = X[i * XD + 4], cz = X[i * XD + 5];
  float dv[8];
  int   di[8];
#pragma unroll
  for (int q = 0; q < 8; ++q) {
    const int j = base + lane + q * 64;
    float dx = __fsub_rn(cx, X[j * XD + 3]);
    float dy = __fsub_rn(cy, X[j * XD + 4]);
    float dz = __fsub_rn(cz, X[j * XD + 5]);
    float d2 = __fadd_rn(__fadd_rn(__fmul_rn(dx, dx), __fmul_rn(dy, dy)), __fmul_rn(dz, dz));
    if (j == i) d2 = 1e9f;
    dv[q] = d2; di[q] = j;
  }
  for (int it = 0; it < KN; ++it) {
    float bv = dv[0]; int bi = di[0];
#pragma unroll
    for (int q = 1; q < 8; ++q)
      if (dv[q] < bv || (dv[q] == bv && di[q] < bi)) { bv = dv[q]; bi = di[q]; }
#pragma unroll
    for (int m = 1; m < 64; m <<= 1) {
      float ov = __shfl_xor(bv, m, 64);
      int   oi = __shfl_xor(bi, m, 64);
      if (ov < bv || (ov == bv && oi < bi)) { bv = ov; bi = oi; }
    }
    if (lane == 0) nbr[i * KN + it] = bi;
    const int rel = bi - base;
    const int oq = rel >> 6;
#pragma unroll
    for (int q = 0; q < 8; ++q)
      if (q == oq && (rel & 63) == lane) dv[q] = 3e38f;
  }
}

// ---------------------------------------------------------------------------
// Fused per-layer edge kernel (r6 topology + packed-cvt VALU diet).
// 7 nodes (63 edges -> 64 rows) per block, 512 threads = 8 waves.
// ---------------------------------------------------------------------------
__global__ __launch_bounds__(512) void edge_layer_kernel(
    const float* __restrict__ Hin,  float* __restrict__ Hout,
    const float* __restrict__ Xin,  float* __restrict__ Xout,
    const int*   __restrict__ nbr,  const float* __restrict__ channel_w,
    const short* __restrict__ PQ,
    const float* __restrict__ eW1,  const float* __restrict__ eb1,
    const float* __restrict__ eb2,  const float* __restrict__ cb1,
    const float* __restrict__ cW2,  const float* __restrict__ cb2,
    const float* __restrict__ nb1,  const float* __restrict__ nb2,
    const short* __restrict__ W2T,  const short* __restrict__ C1T,
    const short* __restrict__ N1T,  const short* __restrict__ N2T,
    const short* __restrict__ W1Tn, short* __restrict__ PQn)
{
  __shared__ __align__(16) short bufA[ROWS * HD];    // h1; later Hout bf16
  __shared__ __align__(16) short bufB[ROWS * HD];    // msg
  __shared__ __align__(16) short nodeA[NPB * 256];   // [Hi | agg]
  __shared__ __align__(16) short uT[NPB * HD];       // node hidden
  __shared__ float scalePart[ROWS][4];
  __shared__ int   nbrS[ROWS];
  short* houtB = bufA;   // bufA dead after G2; reused for Hout bf16

  const int t  = threadIdx.x;
  const int n0 = blockIdx.x * NPB;
  const int nvalid = (NNODE - n0 < NPB) ? (NNODE - n0) : NPB;
  const int evalid = nvalid * KN;

  // ---- P01: nbr + radial (8 thr/row, shfl-reduced) + h1 + nodeA-Hi ----
  {
    const int row  = t >> 3;          // 0..63
    const int part = t & 7;           // 0..7
    const bool rvalid = row < evalid;
    const int nd = row / KN;
    const int jn = rvalid ? nbr[n0 * KN + row] : n0;
    if (part == 0) nbrS[row] = jn;

    float r = 0.f;
    {
      const float* xi = Xin + (size_t)(n0 + ((nd < nvalid) ? nd : 0)) * XD;
      const float* xj = Xin + (size_t)jn * XD;
#pragma unroll
      for (int ii = 0; ii < 6; ++ii) {
        const int e = part + ii * 8;
        if (e < XD) {
          float d = 0.f;
          if (rvalid) d = xi[e] - xj[e];
          r = fmaf(channel_w[e / 3] * d, d, r);
        }
      }
    }
    r += __shfl_xor(r, 1, 64);
    r += __shfl_xor(r, 2, 64);
    r += __shfl_xor(r, 4, 64);

    // nodeA Hi half (224 threads)
    if (t < NPB * (HD / 4)) {
      const int r2 = t >> 5, c4 = t & 31;
      float4 v = make_float4(0.f, 0.f, 0.f, 0.f);
      if (r2 < nvalid) v = ((const float4*)Hin)[(size_t)(n0 + r2) * 32 + c4];
      uint2 u;
      u.x = pkbf(v.x, v.y);
      u.y = pkbf(v.z, v.w);
      *(uint2*)&nodeA[swz256(r2, c4 * 4)] = u;
    }

    // h1 = silu(P[i] + Q[j] + radial*w256 + eb1) -> bufA (this thread: 4 c4)
    const int inode = n0 + ((nd < nvalid) ? nd : 0);
    const short4v* PQv = (const short4v*)PQ;
    const float4* w2564 = (const float4*)(eW1 + 256 * HD);
    const float4* eb14 = (const float4*)eb1;
#pragma unroll
    for (int ii = 0; ii < 4; ++ii) {
      const int c4 = part + ii * 8;
      const short4v ps = PQv[(size_t)inode * 64 + c4];
      const short4v qs = PQv[(size_t)jn * 64 + 32 + c4];
      const float4 w = w2564[c4];
      const float4 bb = eb14[c4];
      uint2 u;
      u.x = pkbf(silu_f(bf2f(ps.x) + bf2f(qs.x) + r * w.x + bb.x),
                 silu_f(bf2f(ps.y) + bf2f(qs.y) + r * w.y + bb.y));
      u.y = pkbf(silu_f(bf2f(ps.z) + bf2f(qs.z) + r * w.z + bb.z),
                 silu_f(bf2f(ps.w) + bf2f(qs.w) + r * w.w + bb.w));
      *(uint2*)&bufA[swz128(row, c4 * 4)] = u;
    }
  }
  __syncthreads();

  const int wid  = t >> 6;       // 0..7
  const int lane = t & 63;
  const int m2 = wid >> 2;       // 0..1
  const int n2 = wid & 3;        // 0..3
  const int lr = lane & 15;
  const int lk = lane >> 4;
  const int rA0 = (m2 * 2) * 16 + lr;
  const int rA1 = rA0 + 16;

  // ---- G2: msg = silu(h1 @ eW2 + eb2) -> bufB ----
  {
    f32x4 acc[2][2] = {};
    const short* b0p = W2T + ((n2 * 2) * 16 + lr) * 128;
    const short* b1p = b0p + 16 * 128;
#pragma unroll
    for (int ks = 0; ks < 4; ++ks) {
      const int k0 = ks * 32 + lk * 8;
      const short8 a0 = *(const short8*)&bufA[swz128(rA0, k0)];
      const short8 a1 = *(const short8*)&bufA[swz128(rA1, k0)];
      const short8 b0 = *(const short8*)(b0p + k0);
      const short8 b1 = *(const short8*)(b1p + k0);
      acc[0][0] = mfma16(a0, b0, acc[0][0]);
      acc[0][1] = mfma16(a0, b1, acc[0][1]);
      acc[1][0] = mfma16(a1, b0, acc[1][0]);
      acc[1][1] = mfma16(a1, b1, acc[1][1]);
    }
#pragma unroll
    for (int ni = 0; ni < 2; ++ni) {
      const int col = (n2 * 2 + ni) * 16 + lr;
      const float bias = eb2[col];
#pragma unroll
      for (int mi = 0; mi < 2; ++mi) {
        const int rb = (m2 * 2 + mi) * 16 + lk * 4;
#pragma unroll
        for (int g = 0; g < 4; ++g)
          bufB[swz128(rb + g, col)] = f2bf(silu_f(acc[mi][ni][g] + bias));
      }
    }
  }
  __syncthreads();

  // ---- G3: scale partials in-register; agg (u32-paired) -> nodeA ----
  {
    f32x4 acc[2][2] = {};
    const short* b0p = C1T + ((n2 * 2) * 16 + lr) * 128;
    const short* b1p = b0p + 16 * 128;
#pragma unroll
    for (int ks = 0; ks < 4; ++ks) {
      const int k0 = ks * 32 + lk * 8;
      const short8 a0 = *(const short8*)&bufB[swz128(rA0, k0)];
      const short8 a1 = *(const short8*)&bufB[swz128(rA1, k0)];
      const short8 b0 = *(const short8*)(b0p + k0);
      const short8 b1 = *(const short8*)(b1p + k0);
      acc[0][0] = mfma16(a0, b0, acc[0][0]);
      acc[0][1] = mfma16(a0, b1, acc[0][1]);
      acc[1][0] = mfma16(a1, b0, acc[1][0]);
      acc[1][1] = mfma16(a1, b1, acc[1][1]);
    }
    float p[2][4];
#pragma unroll
    for (int mi = 0; mi < 2; ++mi)
#pragma unroll
      for (int g = 0; g < 4; ++g) p[mi][g] = 0.f;
#pragma unroll
    for (int ni = 0; ni < 2; ++ni) {
      const int col = (n2 * 2 + ni) * 16 + lr;
      const float bias = cb1[col];
      const float wv = cW2[col];
#pragma unroll
      for (int mi = 0; mi < 2; ++mi)
#pragma unroll
        for (int g = 0; g < 4; ++g)
          p[mi][g] = fmaf(silu_f(acc[mi][ni][g] + bias), wv, p[mi][g]);
    }
#pragma unroll
    for (int m = 1; m < 16; m <<= 1) {
#pragma unroll
      for (int mi = 0; mi < 2; ++mi)
#pragma unroll
        for (int g = 0; g < 4; ++g)
          p[mi][g] += __shfl_xor(p[mi][g], m, 64);
    }
    if (lr == 0) {
#pragma unroll
      for (int mi = 0; mi < 2; ++mi)
#pragma unroll
        for (int g = 0; g < 4; ++g)
          scalePart[(m2 * 2 + mi) * 16 + lk * 4 + g][n2] = p[mi][g];
    }
  }
  if (t < NPB * (HD / 2)) {   // agg: 448 threads, col pairs via u32 reads
    const int r2 = t >> 6, cp = (t & 63) * 2;
    float v0 = 0.f, v1 = 0.f;
#pragma unroll
    for (int k = 0; k < KN; ++k) {
      const unsigned w = *(const unsigned*)&bufB[swz128(r2 * KN + k, cp)];
      v0 += bf2f((short)(w & 0xffffu));
      v1 += bf2f((short)(w >> 16));
    }
    if (r2 >= nvalid) { v0 = 0.f; v1 = 0.f; }
    *(unsigned*)&nodeA[swz256(r2, cp + HD)] = pkbf(v0, v1);
  }
  __syncthreads();

  // ---- P5: NG1 (u = silu([H|agg] @ nW1 + nb1)) ; X update ----
  {
    f32x4 acc = {};
    const short* bp = N1T + (wid * 16 + lr) * 256;
#pragma unroll
    for (int ks = 0; ks < 8; ++ks) {
      const int k0 = ks * 32 + lk * 8;
      short8 a = {0, 0, 0, 0, 0, 0, 0, 0};
      if (lr < NPB) a = *(const short8*)&nodeA[swz256(lr, k0)];
      const short8 b = *(const short8*)(bp + k0);
      acc = mfma16(a, b, acc);
    }
    const int col = wid * 16 + lr;
    const float bias = nb1[col];
#pragma unroll
    for (int g = 0; g < 4; ++g) {
      const int orow = lk * 4 + g;
      if (orow < NPB) uT[swz128(orow, col)] = f2bf(silu_f(acc[g] + bias));
    }
  }
  if (t < NPB * XD) {
    const int nd = t / XD, e = t - nd * XD;
    if (nd < nvalid) {
      const float c2 = cb2[0];
      const float xi = Xin[(size_t)n0 * XD + t];
      float a = 0.f;
#pragma unroll
      for (int k = 0; k < KN; ++k) {
        const int r = nd * KN + k;
        const float sc = ((scalePart[r][0] + scalePart[r][1])
                        + (scalePart[r][2] + scalePart[r][3])) + c2;
        a = fmaf(xi - Xin[(size_t)nbrS[r] * XD + e], sc, a);
      }
      Xout[(size_t)n0 * XD + t] = xi + a / 9.0f;
    }
  }
  __syncthreads();

  // ---- NG2: Hout = Hi + u @ nW2 + nb2 (+ stash bf16 Hout in houtB) ----
  {
    f32x4 acc = {};
    const short* bp = N2T + (wid * 16 + lr) * 128;
#pragma unroll
    for (int ks = 0; ks < 4; ++ks) {
      const int k0 = ks * 32 + lk * 8;
      short8 a = {0, 0, 0, 0, 0, 0, 0, 0};
      if (lr < NPB) a = *(const short8*)&uT[swz128(lr, k0)];
      const short8 b = *(const short8*)(bp + k0);
      acc = mfma16(a, b, acc);
    }
    const int col = wid * 16 + lr;
    const float bias = nb2[col];
#pragma unroll
    for (int g = 0; g < 4; ++g) {
      const int row = lk * 4 + g;
      if (row < nvalid) {
        const float hv = Hin[(size_t)(n0 + row) * HD + col] + acc[g] + bias;
        Hout[(size_t)(n0 + row) * HD + col] = hv;
        if (W1Tn) houtB[swz128(row, col)] = f2bf(hv);
      }
    }
  }

  // ---- PQn: next layer's PQ = Hout @ [W1a|W1b] ----
  if (W1Tn) {
    __syncthreads();
    f32x4 acc[2] = {};
#pragma unroll
    for (int ks = 0; ks < 4; ++ks) {
      const int k0 = ks * 32 + lk * 8;
      short8 a = {0, 0, 0, 0, 0, 0, 0, 0};
      if (lr < NPB) a = *(const short8*)&houtB[swz128(lr, k0)];
#pragma unroll
      for (int ni = 0; ni < 2; ++ni) {
        const int c = (wid * 2 + ni) * 16 + lr;
        const short* bp = (c < HD) ? (W1Tn + c * 256 + k0)
                                   : (W1Tn + (c - HD) * 256 + HD + k0);
        acc[ni] = mfma16(a, *(const short8*)bp, acc[ni]);
      }
    }
#pragma unroll
    for (int ni = 0; ni < 2; ++ni) {
      const int c = (wid * 2 + ni) * 16 + lr;
#pragma unroll
      for (int g = 0; g < 4; ++g) {
        const int row = lk * 4 + g;
        if (row < nvalid) PQn[(size_t)(n0 + row) * 256 + c] = f2bf(acc[ni][g]);
      }
    }
  }
}

// ---------------------------------------------------------------------------
// Output head (4-way ILP unroll)
// ---------------------------------------------------------------------------
__global__ __launch_bounds__(128) void out_kernel(
    const float* __restrict__ H, const float* __restrict__ X,
    const float* __restrict__ oW1, const float* __restrict__ ob1,
    const float* __restrict__ oW2, const float* __restrict__ ob2,
    float* __restrict__ out)
{
  __shared__ float hs[HD];
  __shared__ float u[HD];
  const int i = blockIdx.x, j = threadIdx.x;

  hs[j] = silu_f(H[i * HD + j]);
  __syncthreads();
  float a0 = 0.f, a1 = 0.f, a2 = 0.f, a3 = 0.f;
  for (int k = 0; k < HD; k += 4) {
    a0 = fmaf(hs[k + 0], oW1[(k + 0) * HD + j], a0);
    a1 = fmaf(hs[k + 1], oW1[(k + 1) * HD + j], a1);
    a2 = fmaf(hs[k + 2], oW1[(k + 2) * HD + j], a2);
    a3 = fmaf(hs[k + 3], oW1[(k + 3) * HD + j], a3);
  }
  u[j] = silu_f(ob1[j] + ((a0 + a1) + (a2 + a3)));
  __syncthreads();
  if (j < NCLS) {
    float o0 = 0.f, o1 = 0.f, o2 = 0.f, o3 = 0.f;
    for (int k = 0; k < HD; k += 4) {
      o0 = fmaf(u[k + 0], oW2[(k + 0) * NCLS + j], o0);
      o1 = fmaf(u[k + 1], oW2[(k + 1) * NCLS + j], o1);
      o2 = fmaf(u[k + 2], oW2[(k + 2) * NCLS + j], o2);
      o3 = fmaf(u[k + 3], oW2[(k + 3) * NCLS + j], o3);
    }
    out[i * NCLS + j] = ob2[j] + ((o0 + o1) + (o2 + o3));
  }
  if (j < XD) out[NNODE * NCLS + i * XD + j] = X[i * XD + j];
}

// ---------------------------------------------------------------------------
extern "C" void kernel_launch(void* const* d_in, const int* in_sizes, int n_in,
                              void* d_out, int out_size, void* d_ws, size_t ws_size,
                              hipStream_t stream)
{
  const float* X0       = (const float*)d_in[0];
  const int*   S        = (const int*)  d_in[1];
  const float* embed    = (const float*)d_in[3];
  const float* W_in     = (const float*)d_in[4];
  const float* b_in     = (const float*)d_in[5];
  const float* channelw = (const float*)d_in[6];
  const float* eW1      = (const float*)d_in[7];
  const float* eb1      = (const float*)d_in[8];
  const float* eW2      = (const float*)d_in[9];
  const float* eb2      = (const float*)d_in[10];
  const float* cW1      = (const float*)d_in[11];
  const float* cb1      = (const float*)d_in[12];
  const float* cW2      = (const float*)d_in[13];
  const float* cb2      = (const float*)d_in[14];
  const float* nW1      = (const float*)d_in[15];
  const float* nb1      = (const float*)d_in[16];
  const float* nW2      = (const float*)d_in[17];
  const float* nb2      = (const float*)d_in[18];
  const float* mW1      = (const float*)d_in[19];
  const float* mb1      = (const float*)d_in[20];
  const float* mW2      = (const float*)d_in[21];
  const float* mb2      = (const float*)d_in[22];
  const float* oW1      = (const float*)d_in[23];
  const float* ob1      = (const float*)d_in[24];
  const float* oW2      = (const float*)d_in[25];
  const float* ob2      = (const float*)d_in[26];

  char* ws = (char*)d_ws;
  const size_t HBYTES = (size_t)NNODE * HD * sizeof(float);      // 3,145,728
  const size_t XBYTES = (size_t)NNODE * XD * sizeof(float);      // 1,032,192
  const size_t NBRB   = (size_t)NNODE * KN * sizeof(int);        // 221,184
  const size_t WBFB   = (size_t)WBF_SHORTS * sizeof(short);      // 753,664
  const size_t PQB    = (size_t)NNODE * 256 * sizeof(short);     // 3,145,728
  float* Hb[2] = { (float*)(ws), (float*)(ws + HBYTES) };
  float* Xb[2] = { (float*)(ws + 2 * HBYTES), (float*)(ws + 2 * HBYTES + XBYTES) };
  int*   nbr   = (int*)(ws + 2 * HBYTES + 2 * XBYTES);
  short* Wbf   = (short*)(ws + 2 * HBYTES + 2 * XBYTES + NBRB);
  short* PQb[2] = { (short*)(ws + 2 * HBYTES + 2 * XBYTES + NBRB + WBFB),
                    (short*)(ws + 2 * HBYTES + 2 * XBYTES + NBRB + WBFB + PQB) };

  prep_weights<<<dim3(128, 16), 256, 0, stream>>>(eW1, eW2, cW1, nW1, nW2,
                                                  mW1, mW2, W_in, Wbf);
  copy_kernel<<<(NNODE * XD + 255) / 256, 256, 0, stream>>>(X0, Xb[0], NNODE * XD);

  int hc = 0, xc = 0;
  for (int t = 0; t < 3; ++t) {
    const float* Hmem = (t == 0) ? nullptr : Hb[hc];
    h_init_mfma<<<NNODE / 16, 512, 0, stream>>>(
        embed, S, Wbf + EXOFF + 24576, b_in, Hmem,
        Wbf + EXOFF, mb1, Wbf + EXOFF + 16384, mb2,
        Wbf /* layer-0 eW1T */, Hb[hc ^ 1], PQb[0]);
    hc ^= 1;
    knn_kernel<<<NNODE / 8, 512, 0, stream>>>(Xb[xc], nbr);
    for (int l = 0; l < 3; ++l) {
      const short* Wl = Wbf + (size_t)l * 114688;
      const short* Wn = (l < 2) ? (Wbf + (size_t)(l + 1) * 114688) : nullptr;
      const short* pqr = (l == 1) ? PQb[1] : PQb[0];
      short* pqw = (l == 0) ? PQb[1] : ((l == 1) ? PQb[0] : nullptr);
      edge_layer_kernel<<<EDGE_BLOCKS, 512, 0, stream>>>(
          Hb[hc], Hb[hc ^ 1], Xb[xc], Xb[xc ^ 1], nbr, channelw, pqr,
          eW1 + (size_t)l * 257 * HD, eb1 + (size_t)l * HD,
          eb2 + (size_t)l * HD,  cb1 + (size_t)l * HD,
          cW2 + (size_t)l * HD,  cb2 + (size_t)l,
          nb1 + (size_t)l * HD,  nb2 + (size_t)l * HD,
          Wl + 32768, Wl + 49152, Wl + 65536, Wl + 98304,
          Wn, pqw);
      hc ^= 1; xc ^= 1;
    }
  }
  out_kernel<<<NNODE, HD, 0, stream>>>(Hb[hc], Xb[xc], oW1, ob1, oW2, ob2, (float*)d_out);
}